// Round 2
// baseline (195.041 us; speedup 1.0000x reference)
//
#include <hip/hip_runtime.h>
#include <hip/hip_bf16.h>
#include <cfloat>
#include <cstdint>
#include <cmath>

#define EMBED 768
#define NHEAD 12
#define SEQB  8
#define SEQ   512
#define HDIM  64
#define WMAT  589824  // 768*768

typedef __attribute__((ext_vector_type(8))) short short8;
typedef __attribute__((ext_vector_type(4))) short short4v;
typedef __attribute__((ext_vector_type(4))) float f32x4;

__device__ __forceinline__ short f2bf(float f) {
  uint32_t u = __float_as_uint(f);
  u += 0x7FFF + ((u >> 16) & 1u);
  return (short)(u >> 16);
}

__device__ __forceinline__ void gload_lds16(const void* g, void* l) {
  __builtin_amdgcn_global_load_lds((const __attribute__((address_space(1))) void*)g,
                                   (__attribute__((address_space(3))) void*)l, 16, 0, 0);
}

// ---------------- cast x to bf16 ----------------
__global__ void k_cast_x(const float* __restrict__ x, short* __restrict__ xb) {
  int i = blockIdx.x * blockDim.x + threadIdx.x;
  const int n4 = SEQB * SEQ * EMBED / 4;
  if (i < n4) {
    float4 v = ((const float4*)x)[i];
    short4v o;
    o.x = f2bf(v.x); o.y = f2bf(v.y); o.z = f2bf(v.z); o.w = f2bf(v.w);
    ((short4v*)xb)[i] = o;
  }
}

// ---------------- cast + transpose weights: Wt[mat][n][k] = W[mat][k][n] ----------------
__global__ void k_cast_wt(const float* __restrict__ Wq, const float* __restrict__ Wk,
                          const float* __restrict__ Wv, const float* __restrict__ Wo,
                          short* __restrict__ Wt) {
  __shared__ float tile[32][33];
  const int mat = blockIdx.z;
  const float* src = (mat == 0) ? Wq : (mat == 1) ? Wk : (mat == 2) ? Wv : Wo;
  const int n0 = blockIdx.x * 32, k0 = blockIdx.y * 32;
  const int tx = threadIdx.x & 31, ty = threadIdx.x >> 5;  // 32 x 8
  #pragma unroll
  for (int rr = 0; rr < 4; rr++)
    tile[ty + rr * 8][tx] = src[(size_t)(k0 + ty + rr * 8) * EMBED + n0 + tx];
  __syncthreads();
  short* dst = Wt + (size_t)mat * WMAT;
  #pragma unroll
  for (int rr = 0; rr < 4; rr++)
    dst[(size_t)(n0 + ty + rr * 8) * EMBED + k0 + tx] = f2bf(tile[tx][ty + rr * 8]);
}

// ---------------- GEMM: C[i][j] = sum_k A[i][k]*B[j][k], A:[I][768], B:[J][768] bf16 ----------------
// MODE 0: i = n in [0,1536) (Wq^T|Wk^T rows), j = m=(b,s).  Write Q/K [B,H,S,D] bf16.
// MODE 1: i = m, j = n in [0,768) (Wv^T rows).              Write Vt [B,H,D,S] bf16.
// MODE 2: i = n in [0,768) (Wo^T rows),  j = m.             Write out fp32 [m][768] + bias.
template <int MODE>
__launch_bounds__(256)
__global__ void k_gemm(const short* __restrict__ A, const short* __restrict__ B,
                       short* __restrict__ O0, short* __restrict__ O1,
                       float* __restrict__ OF, const float* __restrict__ bias) {
  __shared__ __attribute__((aligned(16))) short As[128 * 32];
  __shared__ __attribute__((aligned(16))) short Bs[128 * 32];
  const int tid = threadIdx.x;
  const int lane = tid & 63, w = tid >> 6;
  const int g = lane >> 4, c = lane & 15;
  const int wi = (w >> 1) * 64, wj = (w & 1) * 64;
  const int i0 = blockIdx.y * 128, j0 = blockIdx.x * 128;

  f32x4 acc[4][4];
  #pragma unroll
  for (int a = 0; a < 4; a++)
    #pragma unroll
    for (int b2 = 0; b2 < 4; b2++) acc[a][b2] = (f32x4){0.f, 0.f, 0.f, 0.f};

  for (int k0 = 0; k0 < EMBED; k0 += 32) {
    if (k0) __syncthreads();
    #pragma unroll
    for (int it = 0; it < 2; it++) {
      int gi = tid + it * 256;            // 512 granules of 16B per 8KB tile
      int row = gi >> 2, q = gi & 3;
      gload_lds16(A + (size_t)(i0 + row) * EMBED + k0 + q * 8, As + gi * 8);
      gload_lds16(B + (size_t)(j0 + row) * EMBED + k0 + q * 8, Bs + gi * 8);
    }
    __syncthreads();
    short8 aF[4], bF[4];
    #pragma unroll
    for (int mi = 0; mi < 4; mi++) aF[mi] = *(const short8*)&As[(wi + mi * 16 + c) * 32 + g * 8];
    #pragma unroll
    for (int nj = 0; nj < 4; nj++) bF[nj] = *(const short8*)&Bs[(wj + nj * 16 + c) * 32 + g * 8];
    #pragma unroll
    for (int mi = 0; mi < 4; mi++)
      #pragma unroll
      for (int nj = 0; nj < 4; nj++)
        acc[mi][nj] = __builtin_amdgcn_mfma_f32_16x16x32_bf16(aF[mi], bF[nj], acc[mi][nj], 0, 0, 0);
  }

  #pragma unroll
  for (int mi = 0; mi < 4; mi++) {
    int i = i0 + wi + mi * 16 + 4 * g;  // base of 4 consecutive i (the 4 acc regs)
    #pragma unroll
    for (int nj = 0; nj < 4; nj++) {
      int j = j0 + wj + nj * 16 + c;
      f32x4 v = acc[mi][nj];
      if (MODE == 0) {
        int n = i, m = j;
        int b = m >> 9, s = m & 511;
        short* dst = O0; int nn = n;
        if (n >= 768) { dst = O1; nn = n - 768; }
        int h = nn >> 6, d = nn & 63;
        short4v o; o.x = f2bf(v.x); o.y = f2bf(v.y); o.z = f2bf(v.z); o.w = f2bf(v.w);
        *(short4v*)&dst[(size_t)(((b * 12 + h) * 512 + s) * 64 + d)] = o;
      } else if (MODE == 1) {
        int m = i, n = j;
        int b = m >> 9, s = m & 511;
        int h = n >> 6, d = n & 63;
        short4v o; o.x = f2bf(v.x); o.y = f2bf(v.y); o.z = f2bf(v.z); o.w = f2bf(v.w);
        *(short4v*)&O0[(size_t)(((b * 12 + h) * 64 + d) * 512 + s)] = o;
      } else {
        int n = i, m = j;
        float4 bb = *(const float4*)&bias[n];
        float4 o; o.x = v.x + bb.x; o.y = v.y + bb.y; o.z = v.z + bb.z; o.w = v.w + bb.w;
        *(float4*)&OF[(size_t)m * EMBED + n] = o;
      }
    }
  }
}

// ---------------- fused attention: per block (b, h, 64 q-rows) ----------------
__launch_bounds__(256)
__global__ void k_attn(const short* __restrict__ Q, const short* __restrict__ K,
                       const short* __restrict__ Vt, const int* __restrict__ mask,
                       const float* __restrict__ rel_pos, short* __restrict__ attO) {
  __shared__ float bias_lds[1024];
  __shared__ int mask_lds[512];
  __shared__ __attribute__((aligned(16))) short Plds[4][16 * 32];
  const int tid = threadIdx.x;
  const int lane = tid & 63, w = tid >> 6;
  const int g = lane >> 4, c = lane & 15;
  const int q0 = blockIdx.x * 64;
  const int h = blockIdx.y, b = blockIdx.z;
  const int bh = b * 12 + h;
  const short* Qb = Q + (size_t)bh * 512 * 64;
  const short* Kb = K + (size_t)bh * 512 * 64;
  const short* Vb = Vt + (size_t)bh * 64 * 512;

  for (int i = tid; i < 1023; i += 256) bias_lds[i] = rel_pos[i * 12 + h];
  for (int i = tid; i < 512; i += 256) mask_lds[i] = mask[b * 512 + i];
  __syncthreads();

  // Q fragments: A-frag row = c, k-slot sigma = 8g+j, d-chunks dc=0,1
  short8 qf[2];
  #pragma unroll
  for (int dc = 0; dc < 2; dc++)
    qf[dc] = *(const short8*)&Qb[(q0 + w * 16 + c) * 64 + dc * 32 + g * 8];

  int qrow[4], mq[4];
  #pragma unroll
  for (int r = 0; r < 4; r++) { qrow[r] = q0 + w * 16 + 4 * g + r; mq[r] = mask_lds[qrow[r]]; }

  float m_s[4], l_s[4]; f32x4 accO[4];
  #pragma unroll
  for (int r = 0; r < 4; r++) { m_s[r] = -INFINITY; l_s[r] = 0.f; }
  #pragma unroll
  for (int dt = 0; dt < 4; dt++) accO[dt] = (f32x4){0.f, 0.f, 0.f, 0.f};

  for (int k0 = 0; k0 < 512; k0 += 32) {
    float p[2][4];
    #pragma unroll
    for (int ct = 0; ct < 2; ct++) {
      f32x4 s = (f32x4){0.f, 0.f, 0.f, 0.f};
      int krow = k0 + ct * 16 + c;
      #pragma unroll
      for (int dc = 0; dc < 2; dc++) {
        short8 kf = *(const short8*)&Kb[krow * 64 + dc * 32 + g * 8];
        s = __builtin_amdgcn_mfma_f32_16x16x32_bf16(qf[dc], kf, s, 0, 0, 0);
      }
      int mk = mask_lds[krow];
      #pragma unroll
      for (int r = 0; r < 4; r++) {
        int idx = krow - qrow[r] + 511;           // in [0,1022] for S=512
        idx = (idx < 0) ? 0 : (idx > 1022 ? 1022 : idx);
        float v = s[r] * 0.125f + bias_lds[idx];
        if (mq[r] == 0 || mk == 0) v = -FLT_MAX;
        p[ct][r] = v;
      }
    }
    // online softmax per q-row (16 lanes per group hold the 16 k-cols of one ct-tile)
    #pragma unroll
    for (int r = 0; r < 4; r++) {
      float rm = fmaxf(p[0][r], p[1][r]);
      #pragma unroll
      for (int off = 1; off < 16; off <<= 1) rm = fmaxf(rm, __shfl_xor(rm, off));
      float mnew = fmaxf(m_s[r], rm);
      float scale = __expf(m_s[r] - mnew);
      float p0 = __expf(p[0][r] - mnew);
      float p1 = __expf(p[1][r] - mnew);
      p[0][r] = p0; p[1][r] = p1;
      float rs = p0 + p1;
      #pragma unroll
      for (int off = 1; off < 16; off <<= 1) rs += __shfl_xor(rs, off);
      l_s[r] = l_s[r] * scale + rs;
      m_s[r] = mnew;
      #pragma unroll
      for (int dt = 0; dt < 4; dt++) accO[dt][r] *= scale;
    }
    // P -> bf16 -> wave-private LDS [16 q][32 k] row-major (no barrier needed)
    short* Pw = &Plds[w][0];
    #pragma unroll
    for (int ct = 0; ct < 2; ct++)
      #pragma unroll
      for (int r = 0; r < 4; r++)
        Pw[(4 * g + r) * 32 + ct * 16 + c] = f2bf(p[ct][r]);
    short8 pa = *(const short8*)&Pw[c * 32 + g * 8];
    #pragma unroll
    for (int dt = 0; dt < 4; dt++) {
      short8 vf = *(const short8*)&Vb[(dt * 16 + c) * 512 + k0 + g * 8];
      accO[dt] = __builtin_amdgcn_mfma_f32_16x16x32_bf16(pa, vf, accO[dt], 0, 0, 0);
    }
  }
  #pragma unroll
  for (int dt = 0; dt < 4; dt++)
    #pragma unroll
    for (int r = 0; r < 4; r++) {
      float o = accO[dt][r] / l_s[r];
      attO[(size_t)(b * 512 + qrow[r]) * EMBED + h * 64 + dt * 16 + c] = f2bf(o);
    }
}

extern "C" void kernel_launch(void* const* d_in, const int* in_sizes, int n_in,
                              void* d_out, int out_size, void* d_ws, size_t ws_size,
                              hipStream_t stream) {
  const float* x = (const float*)d_in[0];
  const int* mask = (const int*)d_in[1];
  const float* Wq = (const float*)d_in[2];
  const float* Wk = (const float*)d_in[3];
  const float* Wv = (const float*)d_in[4];
  const float* rel_pos = (const float*)d_in[5];
  const float* Wo = (const float*)d_in[6];
  const float* bo = (const float*)d_in[7];
  float* out = (float*)d_out;

  char* ws = (char*)d_ws;
  short* xb = (short*)ws;                                    // 4096*768 bf16 = 6291456 B
  short* Wt = (short*)(ws + 6291456);                        // 4*768*768 bf16 = 4718592 B
  short* Qg = (short*)(ws + 6291456 + 4718592);              // [B,H,S,D] bf16
  short* Kg = Qg + 3145728;                                  // [B,H,S,D]
  short* Vt = Kg + 3145728;                                  // [B,H,D,S]
  short* attO = xb;                                          // alias: xb dead after V-GEMM

  k_cast_x<<<3072, 256, 0, stream>>>(x, xb);
  k_cast_wt<<<dim3(24, 24, 4), 256, 0, stream>>>(Wq, Wk, Wv, Wo, Wt);
  // QK: A = Wt_q|Wt_k rows (i=1536), B = xb (j=4096)
  k_gemm<0><<<dim3(32, 12), 256, 0, stream>>>(Wt, xb, Qg, Kg, nullptr, nullptr);
  // V: A = xb (i=4096), B = Wt_v rows (j=768)
  k_gemm<1><<<dim3(6, 32), 256, 0, stream>>>(xb, Wt + 2 * WMAT, Vt, nullptr, nullptr, nullptr);
  // attention
  k_attn<<<dim3(8, 12, 8), 256, 0, stream>>>(Qg, Kg, Vt, mask, rel_pos, attO);
  // O: A = Wt_o rows (i=768), B = attO (j=4096), fp32 out + bias
  k_gemm<2><<<dim3(32, 6), 256, 0, stream>>>(Wt + 3 * WMAT, attO, nullptr, nullptr, out, bo);
}

// Round 3
// 176.829 us; speedup vs baseline: 1.1030x; 1.1030x over previous
//
#include <hip/hip_runtime.h>
#include <hip/hip_bf16.h>
#include <cfloat>
#include <cstdint>
#include <cmath>

#define EMBED 768
#define NHEAD 12
#define SEQB  8
#define SEQ   512
#define HDIM  64
#define WMAT  589824  // 768*768

typedef __attribute__((ext_vector_type(8))) short short8;
typedef __attribute__((ext_vector_type(4))) short short4v;
typedef __attribute__((ext_vector_type(4))) float f32x4;

__device__ __forceinline__ short f2bf(float f) {
  uint32_t u = __float_as_uint(f);
  u += 0x7FFF + ((u >> 16) & 1u);
  return (short)(u >> 16);
}

__device__ __forceinline__ void gload_lds16(const void* g, void* l) {
  __builtin_amdgcn_global_load_lds((const __attribute__((address_space(1))) void*)g,
                                   (__attribute__((address_space(3))) void*)l, 16, 0, 0);
}

// ---------------- cast x to bf16 ----------------
__global__ void k_cast_x(const float* __restrict__ x, short* __restrict__ xb) {
  int i = blockIdx.x * blockDim.x + threadIdx.x;
  const int n4 = SEQB * SEQ * EMBED / 4;
  if (i < n4) {
    float4 v = ((const float4*)x)[i];
    short4v o;
    o.x = f2bf(v.x); o.y = f2bf(v.y); o.z = f2bf(v.z); o.w = f2bf(v.w);
    ((short4v*)xb)[i] = o;
  }
}

// ---------------- cast + transpose weights: Wt[mat][n][k] = W[mat][k][n] ----------------
__global__ void k_cast_wt(const float* __restrict__ Wq, const float* __restrict__ Wk,
                          const float* __restrict__ Wv, const float* __restrict__ Wo,
                          short* __restrict__ Wt) {
  __shared__ float tile[32][33];
  const int mat = blockIdx.z;
  const float* src = (mat == 0) ? Wq : (mat == 1) ? Wk : (mat == 2) ? Wv : Wo;
  const int n0 = blockIdx.x * 32, k0 = blockIdx.y * 32;
  const int tx = threadIdx.x & 31, ty = threadIdx.x >> 5;  // 32 x 8
  #pragma unroll
  for (int rr = 0; rr < 4; rr++)
    tile[ty + rr * 8][tx] = src[(size_t)(k0 + ty + rr * 8) * EMBED + n0 + tx];
  __syncthreads();
  short* dst = Wt + (size_t)mat * WMAT;
  #pragma unroll
  for (int rr = 0; rr < 4; rr++)
    dst[(size_t)(n0 + ty + rr * 8) * EMBED + k0 + tx] = f2bf(tile[tx][ty + rr * 8]);
}

// ---------------- GEMM: C[i][j] = sum_k A[i][k]*B[j][k], A:[I][768], B:[J][768] bf16 ----
// MODE 0 (QKV): i = n in [0,2304) (Wq^T|Wk^T|Wv^T rows), j = m=(b,s).
//               n<768 -> Q[B,H,S,D]; n<1536 -> K[B,H,S,D]; else -> Vt[B,H,D,S].
// MODE 2 (O):   i = n in [0,768) (Wo^T rows), j = m. fp32 out + bias.
template <int MODE>
__launch_bounds__(256)
__global__ void k_gemm(const short* __restrict__ A, const short* __restrict__ B,
                       short* __restrict__ O0, short* __restrict__ O1,
                       short* __restrict__ O2,
                       float* __restrict__ OF, const float* __restrict__ bias) {
  __shared__ __attribute__((aligned(16))) short As[128 * 32];
  __shared__ __attribute__((aligned(16))) short Bs[128 * 32];
  const int tid = threadIdx.x;
  const int lane = tid & 63, w = tid >> 6;
  const int g = lane >> 4, c = lane & 15;
  const int wi = (w >> 1) * 64, wj = (w & 1) * 64;
  const int i0 = blockIdx.y * 128, j0 = blockIdx.x * 128;

  f32x4 acc[4][4];
  #pragma unroll
  for (int a = 0; a < 4; a++)
    #pragma unroll
    for (int b2 = 0; b2 < 4; b2++) acc[a][b2] = (f32x4){0.f, 0.f, 0.f, 0.f};

  for (int k0 = 0; k0 < EMBED; k0 += 32) {
    if (k0) __syncthreads();
    #pragma unroll
    for (int it = 0; it < 2; it++) {
      int gi = tid + it * 256;            // 512 granules of 16B per 8KB tile
      int row = gi >> 2, q = gi & 3;
      gload_lds16(A + (size_t)(i0 + row) * EMBED + k0 + q * 8, As + gi * 8);
      gload_lds16(B + (size_t)(j0 + row) * EMBED + k0 + q * 8, Bs + gi * 8);
    }
    __syncthreads();
    short8 aF[4], bF[4];
    #pragma unroll
    for (int mi = 0; mi < 4; mi++) aF[mi] = *(const short8*)&As[(wi + mi * 16 + c) * 32 + g * 8];
    #pragma unroll
    for (int nj = 0; nj < 4; nj++) bF[nj] = *(const short8*)&Bs[(wj + nj * 16 + c) * 32 + g * 8];
    #pragma unroll
    for (int mi = 0; mi < 4; mi++)
      #pragma unroll
      for (int nj = 0; nj < 4; nj++)
        acc[mi][nj] = __builtin_amdgcn_mfma_f32_16x16x32_bf16(aF[mi], bF[nj], acc[mi][nj], 0, 0, 0);
  }

  #pragma unroll
  for (int mi = 0; mi < 4; mi++) {
    int i = i0 + wi + mi * 16 + 4 * g;  // base of 4 consecutive i (the 4 acc regs)
    #pragma unroll
    for (int nj = 0; nj < 4; nj++) {
      int j = j0 + wj + nj * 16 + c;
      f32x4 v = acc[mi][nj];
      if (MODE == 0) {
        int n = i, m = j;
        int b = m >> 9, s = m & 511;
        if (n < 1536) {
          short* dst = O0; int nn = n;
          if (n >= 768) { dst = O1; nn -= 768; }
          int h = nn >> 6, d = nn & 63;
          short4v o; o.x = f2bf(v.x); o.y = f2bf(v.y); o.z = f2bf(v.z); o.w = f2bf(v.w);
          *(short4v*)&dst[(size_t)(((b * 12 + h) * 512 + s) * 64 + d)] = o;
        } else {
          int nn = n - 1536;
          int h = nn >> 6, d = nn & 63;
          size_t base = ((size_t)(b * 12 + h) * 64 + d) * 512 + s;
          O2[base] = f2bf(v.x); O2[base + 512] = f2bf(v.y);
          O2[base + 1024] = f2bf(v.z); O2[base + 1536] = f2bf(v.w);
        }
      } else {
        int n = i, m = j;
        float4 bb = *(const float4*)&bias[n];
        float4 o; o.x = v.x + bb.x; o.y = v.y + bb.y; o.z = v.z + bb.z; o.w = v.w + bb.w;
        *(float4*)&OF[(size_t)m * EMBED + n] = o;
      }
    }
  }
}

// ---------------- fused attention: per block (b, h, 64 q-rows), fixed-offset softmax ---
__launch_bounds__(256)
__global__ void k_attn(const short* __restrict__ Q, const short* __restrict__ K,
                       const short* __restrict__ Vt, const int* __restrict__ mask,
                       const float* __restrict__ rel_pos, short* __restrict__ attO) {
  __shared__ float bias_lds[1024];
  __shared__ int mask_lds[512];
  __shared__ __attribute__((aligned(16))) short Plds[4][16 * 32];
  const int tid = threadIdx.x;
  const int lane = tid & 63, w = tid >> 6;
  const int g = lane >> 4, c = lane & 15;
  // XCD-affinity: linear id % 8 == bh % 8 (96 % 8 == 0), so all 8 q-blocks of a
  // (b,h) land on one XCD -> K/V L2-resident per XCD.
  const int bid = blockIdx.x;
  const int q0 = (bid / 96) * 64;
  const int bh = bid % 96;
  const int b = bh / 12, h = bh % 12;
  const short* Qb = Q + (size_t)bh * (512 * 64);
  const short* Kb = K + (size_t)bh * (512 * 64);
  const short* Vb = Vt + (size_t)bh * (64 * 512);

  // bias folded with the fixed softmax offset (exp(s/8 + bias - 16))
  for (int i = tid; i < 1023; i += 256) bias_lds[i] = rel_pos[i * 12 + h] - 16.0f;
  for (int i = tid; i < 512; i += 256) mask_lds[i] = mask[b * 512 + i];
  __syncthreads();

  short8 qf[2];
  #pragma unroll
  for (int dc = 0; dc < 2; dc++)
    qf[dc] = *(const short8*)&Qb[(q0 + w * 16 + c) * 64 + dc * 32 + g * 8];

  int qrow[4], mq[4], bbase[4];
  #pragma unroll
  for (int r = 0; r < 4; r++) {
    qrow[r] = q0 + w * 16 + 4 * g + r;
    mq[r] = mask_lds[qrow[r]];
    bbase[r] = 511 - qrow[r];
  }

  float l_part[4];
  f32x4 accO[4];
  #pragma unroll
  for (int r = 0; r < 4; r++) l_part[r] = 0.f;
  #pragma unroll
  for (int dt = 0; dt < 4; dt++) accO[dt] = (f32x4){0.f, 0.f, 0.f, 0.f};

  short8 kf[4], vf[4], nkf[4], nvf[4];
  #define LOADKV(K0, KK, VV)                                                        \
    {                                                                               \
      _Pragma("unroll")                                                             \
      for (int ct = 0; ct < 2; ct++)                                                \
        _Pragma("unroll")                                                           \
        for (int dc = 0; dc < 2; dc++)                                              \
          KK[ct * 2 + dc] = *(const short8*)&Kb[((K0) + ct * 16 + c) * 64 + dc * 32 + g * 8]; \
      _Pragma("unroll")                                                             \
      for (int dt = 0; dt < 4; dt++)                                                \
        VV[dt] = *(const short8*)&Vb[(dt * 16 + c) * 512 + (K0) + g * 8];           \
    }
  LOADKV(0, kf, vf);

  short* Pw = &Plds[w][0];
  const int rdoff = c * 32 + ((g * 8) ^ (((c >> 2) & 3) << 3));  // swizzled read base

  for (int k0 = 0; k0 < 512; k0 += 32) {
    if (k0 + 32 < 512) LOADKV(k0 + 32, nkf, nvf);
    float p[2][4];
    #pragma unroll
    for (int ct = 0; ct < 2; ct++) {
      f32x4 s = (f32x4){0.f, 0.f, 0.f, 0.f};
      s = __builtin_amdgcn_mfma_f32_16x16x32_bf16(qf[0], kf[ct * 2 + 0], s, 0, 0, 0);
      s = __builtin_amdgcn_mfma_f32_16x16x32_bf16(qf[1], kf[ct * 2 + 1], s, 0, 0, 0);
      int krow = k0 + ct * 16 + c;
      int mk = mask_lds[krow];
      #pragma unroll
      for (int r = 0; r < 4; r++) {
        float arg = fmaf(s[r], 0.125f, bias_lds[krow + bbase[r]]);
        float pv = __expf(arg);
        if ((mq[r] & mk) == 0) pv = 0.f;
        p[ct][r] = pv;
        l_part[r] += pv;
      }
    }
    // pack P -> bf16 -> wave-private LDS, XOR-swizzled (write row = 4g+r)
    #pragma unroll
    for (int ct = 0; ct < 2; ct++)
      #pragma unroll
      for (int r = 0; r < 4; r++)
        Pw[(4 * g + r) * 32 + ((ct * 16 + c) ^ (g << 3))] = f2bf(p[ct][r]);
    short8 pa = *(const short8*)&Pw[rdoff];
    #pragma unroll
    for (int dt = 0; dt < 4; dt++)
      accO[dt] = __builtin_amdgcn_mfma_f32_16x16x32_bf16(pa, vf[dt], accO[dt], 0, 0, 0);
    #pragma unroll
    for (int i = 0; i < 4; i++) { kf[i] = nkf[i]; vf[i] = nvf[i]; }
  }

  float inv[4];
  #pragma unroll
  for (int r = 0; r < 4; r++) {
    float lr = l_part[r];
    #pragma unroll
    for (int off = 1; off < 16; off <<= 1) lr += __shfl_xor(lr, off);
    inv[r] = 1.0f / lr;
  }
  #pragma unroll
  for (int dt = 0; dt < 4; dt++)
    #pragma unroll
    for (int r = 0; r < 4; r++)
      attO[(size_t)(b * 512 + qrow[r]) * EMBED + h * 64 + dt * 16 + c] =
          f2bf(accO[dt][r] * inv[r]);
}

extern "C" void kernel_launch(void* const* d_in, const int* in_sizes, int n_in,
                              void* d_out, int out_size, void* d_ws, size_t ws_size,
                              hipStream_t stream) {
  const float* x = (const float*)d_in[0];
  const int* mask = (const int*)d_in[1];
  const float* Wq = (const float*)d_in[2];
  const float* Wk = (const float*)d_in[3];
  const float* Wv = (const float*)d_in[4];
  const float* rel_pos = (const float*)d_in[5];
  const float* Wo = (const float*)d_in[6];
  const float* bo = (const float*)d_in[7];
  float* out = (float*)d_out;

  char* ws = (char*)d_ws;
  short* xb = (short*)ws;                                    // 4096*768 bf16 = 6291456 B
  short* Wt = (short*)(ws + 6291456);                        // 4*768*768 bf16 = 4718592 B
  short* Qg = (short*)(ws + 6291456 + 4718592);              // [B,H,S,D] bf16
  short* Kg = Qg + 3145728;                                  // [B,H,S,D]
  short* Vt = Kg + 3145728;                                  // [B,H,D,S]
  short* attO = xb;                                          // alias: xb dead after QKV-GEMM

  k_cast_x<<<3072, 256, 0, stream>>>(x, xb);
  k_cast_wt<<<dim3(24, 24, 4), 256, 0, stream>>>(Wq, Wk, Wv, Wo, Wt);
  // QKV fused: A = Wt_q|Wt_k|Wt_v rows (i=2304), B = xb (j=4096)
  k_gemm<0><<<dim3(32, 18), 256, 0, stream>>>(Wt, xb, Qg, Kg, Vt, nullptr, nullptr);
  // attention (1D grid, XCD-affinity remap inside)
  k_attn<<<768, 256, 0, stream>>>(Qg, Kg, Vt, mask, rel_pos, attO);
  // O: A = Wt_o rows (i=768), B = attO (j=4096), fp32 out + bias
  k_gemm<2><<<dim3(32, 6), 256, 0, stream>>>(Wt + 3 * WMAT, attO, nullptr, nullptr, nullptr, out, bo);
}